// Round 8
// baseline (109.132 us; speedup 1.0000x reference)
//
#include <hip/hip_runtime.h>

// Problem constants
#define IMG_H 512
#define IMG_W 512
#define IMG_SZ (IMG_H * IMG_W)
#define NKH 32
#define NKW 32
#define NK 1024
#define NTT 33               // 16x16 tiles per dim of 528x528 padded image
#define NTILE (NTT * NTT)    // 1089 blocks (one per tile, all 64 batches)

typedef __attribute__((address_space(3))) char lds_char_t;
typedef const __attribute__((address_space(1))) char g_char_t;

// out[b][n] = bias[n]  (main kernel atomically accumulates onto this)
__global__ __launch_bounds__(256)
void bslc_init(const float* __restrict__ bias, float* __restrict__ out)
{
    const int g = blockIdx.x * 256 + threadIdx.x;   // b*1024 + n
    out[g] = bias[g & (NK - 1)];
}

// Tile (tr,tc) = quadrant (qr,qc) of window (tr-qr, tc-qc): bijective.
// Block = one tile x 64 batches in 4 phases of 16. LDS: 2x16KB x (double
// buffer) + 4KB w = 36KB -> 4 blocks/CU.
// 2-phase pipeline (T3-lite): issue DMA stage of phase bg+1 BEFORE computing
// phase bg from the other buffer; one __syncthreads per phase, so the drained
// stage had the whole compute phase to land. Border tiles: T14 split (loads
// issued pre-compute into regs, ds_write post-compute).
// Swizzle (rule #21, both sides): DMA dest linear (slot=lane), source chunk
// c = lane^bl (involution) -> compute reads slot = kq^bl. Weights read as
// 4-addr 16-lane broadcasts (conflict-free).
__global__ __launch_bounds__(256, 4)
void bslc_main(const float* __restrict__ x,
               const float* __restrict__ w,
               float* __restrict__ out)
{
    __shared__ float4 xs[2][16 * 64];   // 2 x 16 KiB: [buf][bl][slot]
    __shared__ float4 wl[4 * 64];       // 4 KiB: [q][kq]

    // Bijective XCD-chunked swizzle (m204): 1089 = 8*136 + 1.
    const int hw = blockIdx.x;
    const int xcd = hw & 7, sl = hw >> 3;
    const int q8 = NTILE >> 3, r8 = NTILE & 7;        // 136, 1
    const int work = (xcd < r8 ? xcd * (q8 + 1)
                               : r8 * (q8 + 1) + (xcd - r8) * q8) + sl;
    const int tr = work / NTT, tc = work % NTT;

    const int t = threadIdx.x, lane = t & 63, wv = t >> 6;

    // This wave's window (quadrant wv of window (tr-qr, tc-qc)).
    const int qr = wv >> 1, qc = wv & 1;
    const int nr = tr - qr, nc = tc - qc;
    const bool valid = (nr >= 0) & (nr < NKH) & (nc >= 0) & (nc < NKW);
    const int n = nr * NKW + nc;

    // ---- weight stage: 1 DMA instr per valid wave (dest linear in lane) ----
    if (valid) {
        const float* gw = w + (size_t)n * 1024
                        + (size_t)(qr * 16 + (lane >> 2)) * 32
                        + qc * 16 + (lane & 3) * 4;
        __builtin_amdgcn_global_load_lds(
            (g_char_t*)gw, (lds_char_t*)&wl[wv * 64], 16, 0, 0);
    } else {
        wl[wv * 64 + lane] = make_float4(0.f, 0.f, 0.f, 0.f);
    }

    const int r0 = tr * 16 - 8, c0 = tc * 16 - 8;
    const bool interior = (tr >= 1) & (tr <= 31) & (tc >= 1) & (tc <= 31);
    const int p = lane >> 4, bl16 = lane & 15;

    // ---- staging helpers ----
    auto stage_dma = [&](int bg, int buf) {
#pragma unroll
        for (int ii = 0; ii < 4; ++ii) {
            const int bl = 4 * ii + wv;              // wave-uniform
            const int c  = lane ^ bl;                // pre-swizzled source chunk
            const float* gp = x + (size_t)(bg * 16 + bl) * IMG_SZ
                            + (size_t)(r0 + (c >> 2)) * IMG_W
                            + c0 + (c & 3) * 4;
            __builtin_amdgcn_global_load_lds(
                (g_char_t*)gp, (lds_char_t*)&xs[buf][bl * 64], 16, 0, 0);
        }
    };
    auto border_load = [&](int bg, float4* brd) {
#pragma unroll
        for (int ii = 0; ii < 4; ++ii) {
            const int bl = 4 * ii + wv;
            const int c  = lane ^ bl;
            const int rimg = r0 + (c >> 2);
            const int cimg = c0 + (c & 3) * 4;
            float4 v = make_float4(0.f, 0.f, 0.f, 0.f);
            if (rimg >= 0 && rimg < IMG_H && cimg >= 0 && cimg < IMG_W)
                v = *reinterpret_cast<const float4*>(
                    x + (size_t)(bg * 16 + bl) * IMG_SZ
                      + (size_t)rimg * IMG_W + cimg);
            brd[ii] = v;
        }
    };
    auto border_write = [&](int buf, const float4* brd) {
#pragma unroll
        for (int ii = 0; ii < 4; ++ii) {
            const int bl = 4 * ii + wv;
            xs[buf][bl * 64 + lane] = brd[ii];       // slot=lane, chunk=lane^bl
        }
    };

    // ---- prologue: stage phase 0 into buffer 0 ----
    float4 brd[4];
    if (interior) {
        stage_dma(0, 0);
    } else {
        border_load(0, brd);
        border_write(0, brd);
    }
    __syncthreads();

    // ---- 4 pipelined phases ----
#pragma unroll
    for (int bg = 0; bg < 4; ++bg) {
        const int cur = bg & 1, nxt = cur ^ 1;

        // Issue next phase's stage first (overlaps with compute below).
        if (bg < 3) {
            if (interior) stage_dma(bg + 1, nxt);
            else          border_load(bg + 1, brd);
        }

        // Compute current phase: LDS-only inner loop.
        float a0 = 0.f, a1 = 0.f, a2 = 0.f, a3 = 0.f;
#pragma unroll
        for (int j = 0; j < 16; ++j) {
            const int kq = 4 * j + p;                // bank-spread across p
            const float4 xv  = xs[cur][bl16 * 64 + (kq ^ bl16)];
            const float4 wv4 = wl[wv * 64 + kq];     // 4-addr broadcast read
            a0 = fmaf(xv.x, wv4.x, a0);
            a1 = fmaf(xv.y, wv4.y, a1);
            a2 = fmaf(xv.z, wv4.z, a2);
            a3 = fmaf(xv.w, wv4.w, a3);
        }
        float s = (a0 + a1) + (a2 + a3);
        s += __shfl_xor(s, 16, 64);                  // combine parts
        s += __shfl_xor(s, 32, 64);
        if (valid && p == 0)                         // lanes 0..15: batch bl16
            atomicAdd(&out[(size_t)(bg * 16 + bl16) * NK + n], s);

        // Border: T14 write-late (loads had the whole compute to land).
        if (bg < 3 && !interior) border_write(nxt, brd);

        __syncthreads();
    }
}

extern "C" void kernel_launch(void* const* d_in, const int* in_sizes, int n_in,
                              void* d_out, int out_size, void* d_ws, size_t ws_size,
                              hipStream_t stream) {
    const float* x    = (const float*)d_in[0];  // (64,1,512,512) fp32
    const float* wgt  = (const float*)d_in[1];  // (1024,1024) fp32
    const float* bias = (const float*)d_in[2];  // (1024,) fp32
    float* out        = (float*)d_out;          // (64,32,32) fp32

    bslc_init<<<dim3(64 * NK / 256), 256, 0, stream>>>(bias, out);
    bslc_main<<<dim3(NTILE), 256, 0, stream>>>(x, wgt, out);
}

// Round 10
// 107.834 us; speedup vs baseline: 1.0120x; 1.0120x over previous
//
#include <hip/hip_runtime.h>

// Problem constants
#define IMG_H 512
#define IMG_W 512
#define IMG_SZ (IMG_H * IMG_W)
#define NK 1024          // 32x32 windows
#define NWAVE 4096       // 512 rows x 8 batch-octets
#define NBLK (NWAVE / 4) // 1024 blocks of 256 threads

// out[b][n] = bias[n]  (main kernel atomically accumulates onto this)
__global__ __launch_bounds__(256)
void bslc_init(const float* __restrict__ bias, float* __restrict__ out)
{
    const int g = blockIdx.x * 256 + threadIdx.x;   // b*1024 + n
    out[g] = bias[g & (NK - 1)];
}

// Streaming scatter kernel. Wave = (image row r, batch octet). Lane L covers
// pixels c in [8L, 8L+8) -> padded col cp = c+8 in [8L+8, 8L+16).
//   col windows: nc_hi = (L+1)>>1 (kc = kc0 + j, kc0 = L odd ? 0 : 8),
//                nc_lo = nc_hi - 1 (kc0 + 16). Lane 0: no lo; lane 63: no hi.
//   row windows: cpr = r+8; nr_hi = cpr>>4 (kr = cpr&15), nr_lo = nr_hi-1
//                (kr+16). r<8: no lo; r>=504: no hi.  (wave-uniform)
// Per batch: two linear float4 x loads (wave reads contiguous 2KB), 32 FMAs
// into 4 accumulators, 4-shfl reduction, 2 coalesced atomic instructions
// (33 lanes: lane 0 -> nc 0, odd lanes 1..61 -> nc (L+1)/2).
// Window nc sums hi over lanes {2nc-1,2nc} and lo over {2nc+1,2nc+2}.
__global__ __launch_bounds__(256)
void bslc_main(const float* __restrict__ x,
               const float* __restrict__ w,
               float* __restrict__ out)
{
    // XCD swizzle: 1024 blocks = 8 XCDs x 128 -> waves sharing a row land on
    // the same XCD (w lines L2-shared).
    const int bid  = blockIdx.x;
    const int work = (bid & 7) * (NBLK / 8) + (bid >> 3);
    const int gw   = work * 4 + (threadIdx.x >> 6);   // 0..4095
    const int lane = threadIdx.x & 63;

    const int r  = gw >> 3;          // image row 0..511
    const int b0 = (gw & 7) * 8;     // batches b0..b0+7

    const int cpr = r + 8;
    const int nrh = cpr >> 4, krh = cpr & 15;
    const int nrl = nrh - 1,  krl = krh + 16;
    const bool vh = (nrh < 32);      // wave-uniform
    const bool vl = (nrl >= 0);

    const int  m    = (lane + 1) >> 1;        // nc_hi
    const int  kc0  = (lane & 1) ? 0 : 8;
    const bool vhc  = (m < 32);               // lane 63: hi invalid
    const bool vlc  = (m >= 1);               // lane 0:  lo invalid

    const float4 z4 = make_float4(0.f, 0.f, 0.f, 0.f);
    float4 whh[2] = {z4, z4}, whl[2] = {z4, z4};   // row-hi x col-{hi,lo}
    float4 wlh[2] = {z4, z4}, wll[2] = {z4, z4};   // row-lo x col-{hi,lo}

    if (vh) {
        if (vhc) {
            const float* p = w + (size_t)(nrh * 32 + m) * 1024 + krh * 32 + kc0;
            whh[0] = *(const float4*)p;  whh[1] = *(const float4*)(p + 4);
        }
        if (vlc) {
            const float* p = w + (size_t)(nrh * 32 + m - 1) * 1024 + krh * 32 + kc0 + 16;
            whl[0] = *(const float4*)p;  whl[1] = *(const float4*)(p + 4);
        }
    }
    if (vl) {
        if (vhc) {
            const float* p = w + (size_t)(nrl * 32 + m) * 1024 + krl * 32 + kc0;
            wlh[0] = *(const float4*)p;  wlh[1] = *(const float4*)(p + 4);
        }
        if (vlc) {
            const float* p = w + (size_t)(nrl * 32 + m - 1) * 1024 + krl * 32 + kc0 + 16;
            wll[0] = *(const float4*)p;  wll[1] = *(const float4*)(p + 4);
        }
    }

    const float* xr = x + (size_t)r * IMG_W + lane * 8;

#define ACC4(xv, wv, a)                                                  \
    { a = fmaf((xv).x, (wv).x, a); a = fmaf((xv).y, (wv).y, a);          \
      a = fmaf((xv).z, (wv).z, a); a = fmaf((xv).w, (wv).w, a); }

#pragma unroll 2
    for (int bb = 0; bb < 8; ++bb) {
        const int b = b0 + bb;
        const float* xp = xr + (size_t)b * IMG_SZ;
        const float4 x0 = *(const float4*)xp;
        const float4 x1 = *(const float4*)(xp + 4);

        float ahh = 0.f, ahl = 0.f, alh = 0.f, alo = 0.f;
        ACC4(x0, whh[0], ahh); ACC4(x1, whh[1], ahh);
        ACC4(x0, whl[0], ahl); ACC4(x1, whl[1], ahl);
        ACC4(x0, wlh[0], alh); ACC4(x1, wlh[1], alh);
        ACC4(x0, wll[0], alo); ACC4(x1, wll[1], alo);

        // Asymmetric window reduction + scatter (per valid row-window).
        // s(nc=0) @lane0 = hi(0) + lo2(1); s(nc>=1) @lane(2nc-1, odd) =
        // hi2 + lo2(+2), where hi2/lo2 are +1-neighbor sums (lane63 masked).
        {
            const bool act = (lane == 0) || ((lane & 1) && lane <= 61);
            if (vh) {
                float hiN = __shfl_down(ahh, 1, 64);
                float loN = __shfl_down(ahl, 1, 64);
                float hi2 = ahh + ((lane == 63) ? 0.f : hiN);
                float lo2 = ahl + ((lane == 63) ? 0.f : loN);
                float lo21 = __shfl_down(lo2, 1, 64);
                float lo22 = __shfl_down(lo2, 2, 64);
                float s  = (lane == 0) ? (ahh + lo21) : (hi2 + lo22);
                int   nc = (lane == 0) ? 0 : ((lane + 1) >> 1);
                if (act)
                    atomicAdd(&out[(size_t)b * NK + nrh * 32 + nc], s);
            }
            if (vl) {
                float hiN = __shfl_down(alh, 1, 64);
                float loN = __shfl_down(alo, 1, 64);
                float hi2 = alh + ((lane == 63) ? 0.f : hiN);
                float lo2 = alo + ((lane == 63) ? 0.f : loN);
                float lo21 = __shfl_down(lo2, 1, 64);
                float lo22 = __shfl_down(lo2, 2, 64);
                float s  = (lane == 0) ? (alh + lo21) : (hi2 + lo22);
                int   nc = (lane == 0) ? 0 : ((lane + 1) >> 1);
                if (act)
                    atomicAdd(&out[(size_t)b * NK + nrl * 32 + nc], s);
            }
        }
    }
#undef ACC4
}

extern "C" void kernel_launch(void* const* d_in, const int* in_sizes, int n_in,
                              void* d_out, int out_size, void* d_ws, size_t ws_size,
                              hipStream_t stream) {
    const float* x    = (const float*)d_in[0];  // (64,1,512,512) fp32
    const float* wgt  = (const float*)d_in[1];  // (1024,1024) fp32
    const float* bias = (const float*)d_in[2];  // (1024,) fp32
    float* out        = (float*)d_out;          // (64,32,32) fp32

    bslc_init<<<dim3(64 * NK / 256), 256, 0, stream>>>(bias, out);
    bslc_main<<<dim3(NBLK), 256, 0, stream>>>(x, wgt, out);
}